// Round 12
// baseline (109.841 us; speedup 1.0000x reference)
//
#include <hip/hip_runtime.h>
#include <hip/hip_fp16.h>
#include <math.h>

#define BATCH 8
#define DZ    32
#define NWH   48
#define NBOX  (NWH*NWH)          // 2304
#define KMAX  25
#define PIX   (384*384)          // 147456 per (k,b) slab
#define GRID  768                // 3 blocks/CU x 256 CU (LDS 51200 -> exactly co-resident)
#define UNITS 1152               // (BATCH*PIX)/1024

typedef float vfloat4 __attribute__((ext_vector_type(4)));

__device__ __forceinline__ float sigm(float x) { return 1.0f / (1.0f + expf(-x)); }
__device__ __forceinline__ float sp_fast(float x) {
    return fmaxf(x, 0.0f) + __logf(1.0f + __expf(-fabsf(x)));
}

struct NmsSh {
    vfloat4 boxS[NBOX];                  // 36864 B
    float   prS[NBOX];                   //  9216 B
    unsigned long long keyB[2][4];
    int idxA[KMAX], okA[KMAX];
};
union SharedU {
    NmsSh nms;                           // ~46.5 KB (blocks 0-7, before big phase)
    uint2 spL[KMAX * 256];               // 51200 B  (thread-private f16 sp slots)
};

// ---- stage: read 25 slabs of a 1024-px unit, softplus->f16 LDS, return m ----
__device__ __forceinline__ vfloat4 stage_unit(const float* __restrict__ wlg, size_t jb,
                                              uint2* spL, int t) {
    const size_t stride = (size_t)BATCH * PIX;
    const float* base = wlg + jb;
    vfloat4 S = {0.f, 0.f, 0.f, 0.f};
    #pragma unroll
    for (int k = 0; k < KMAX; ++k) {
        vfloat4 v = *(const vfloat4*)(base + (size_t)k * stride);
        float sx = sp_fast(v.x), sy = sp_fast(v.y), sz = sp_fast(v.z), sw = sp_fast(v.w);
        S.x += sx; S.y += sy; S.z += sz; S.w += sw;
        __half2 h01 = __floats2half2_rn(sx, sy);
        __half2 h23 = __floats2half2_rn(sz, sw);
        uint2 pk; pk.x = *(unsigned int*)&h01; pk.y = *(unsigned int*)&h23;
        spL[k * 256 + t] = pk;
    }
    vfloat4 m;
    float ex = __expf(-2.f*S.x), ey = __expf(-2.f*S.y),
          ez = __expf(-2.f*S.z), ew = __expf(-2.f*S.w);
    m.x = (1.f - ex) * __builtin_amdgcn_rcpf(1.f + ex) * __builtin_amdgcn_rcpf(fmaxf(S.x, 1e-6f));
    m.y = (1.f - ey) * __builtin_amdgcn_rcpf(1.f + ey) * __builtin_amdgcn_rcpf(fmaxf(S.y, 1e-6f));
    m.z = (1.f - ez) * __builtin_amdgcn_rcpf(1.f + ez) * __builtin_amdgcn_rcpf(fmaxf(S.z, 1e-6f));
    m.w = (1.f - ew) * __builtin_amdgcn_rcpf(1.f + ew) * __builtin_amdgcn_rcpf(fmaxf(S.w, 1e-6f));
    return m;
}

__device__ __forceinline__ void write_unit(float* __restrict__ out, const float* __restrict__ pfb,
                                           size_t jb, const uint2* spL, int t, vfloat4 m) {
    const size_t stride = (size_t)BATCH * PIX;
    float* ob = out + jb;
    #pragma unroll
    for (int k = 0; k < KMAX; ++k) {
        uint2 pk = spL[k * 256 + t];
        __half2 h01 = *(__half2*)&pk.x;
        __half2 h23 = *(__half2*)&pk.y;
        float2 a = __half22float2(h01);
        float2 d = __half22float2(h23);
        float c = pfb[k];
        vfloat4 o = { c * m.x * a.x, c * m.y * a.y, c * m.z * d.x, c * m.w * d.y };
        *(vfloat4*)(ob + (size_t)k * stride) = o;
    }
}

__global__ __launch_bounds__(256, 3) void fused_kernel(
    const float* __restrict__ z, const float* __restrict__ wz, const float* __restrict__ bz,
    const float* __restrict__ lg, const float* __restrict__ wl, const float* __restrict__ bl,
    const float* __restrict__ wlg, float* __restrict__ pfT, int* __restrict__ flag,
    float* __restrict__ out)
{
    __shared__ SharedU sh;
    const int blk = blockIdx.x, t = threadIdx.x;

    // ============ blocks 0-7: conv (batch=blk) -> LDS, then NMS, then flag ============
    if (blk < 8) {
        const int b = blk;
        #pragma unroll 1
        for (int g = t; g < 576; g += 256) {
            int iw = g / 12, ihq = g % 12;
            const float* zb = z  + (((size_t)b * DZ) * NWH + iw) * NWH + ihq * 4;
            const float* lb = lg + (((size_t)b * DZ) * NWH + iw) * NWH + ihq * 4;
            float b0 = bz[0], b1 = bz[1], b2 = bz[2], b3 = bz[3], blg = bl[0];
            vfloat4 a0 = {b0,b0,b0,b0}, a1 = {b1,b1,b1,b1}, a2 = {b2,b2,b2,b2},
                    a3 = {b3,b3,b3,b3}, al = {blg,blg,blg,blg};
            #pragma unroll 8
            for (int d = 0; d < DZ; ++d) {
                vfloat4 zv = *(const vfloat4*)(zb + (size_t)d * NBOX);
                vfloat4 lv = *(const vfloat4*)(lb + (size_t)d * NBOX);
                float w0 = wz[d], w1 = wz[32+d], w2 = wz[64+d], w3 = wz[96+d], wv = wl[d];
                a0 += zv * w0; a1 += zv * w1; a2 += zv * w2; a3 += zv * w3; al += lv * wv;
            }
            float t0v[4] = {a0.x,a0.y,a0.z,a0.w};
            float t1v[4] = {a1.x,a1.y,a1.z,a1.w};
            float t2v[4] = {a2.x,a2.y,a2.z,a2.w};
            float t3v[4] = {a3.x,a3.y,a3.z,a3.w};
            float alv[4] = {al.x,al.y,al.z,al.w};
            #pragma unroll
            for (int c = 0; c < 4; ++c) {
                float tx = sigm(t0v[c]), ty = sigm(t1v[c]), tw = sigm(t2v[c]), th = sigm(t3v[c]);
                float bx = 8.0f * ((float)iw + tx);
                float by = 8.0f * ((float)(ihq*4 + c) + ty);
                float bw = 12.0f + 36.0f * tw;
                float bh = 12.0f + 36.0f * th;
                int n = iw * NWH + ihq * 4 + c;
                sh.nms.boxS[n] = (vfloat4){bx - 0.5f*bw, by - 0.5f*bh, bx + 0.5f*bw, by + 0.5f*bh};
                sh.nms.prS[n]  = sigm(alv[c]);
            }
        }
        __syncthreads();

        float mkv[9];
        #pragma unroll
        for (int s = 0; s < 9; ++s) {
            float p = sh.nms.prS[s * 256 + t];
            mkv[s] = (p > 0.1f) ? p : -INFINITY;
        }

        float sx1=0.f, sy1=0.f, sx2=0.f, sy2=0.f, sar=0.f;
        for (int k = 0; k < KMAX; ++k) {
            unsigned long long best = 0ULL;
            #pragma unroll
            for (int s = 0; s < 9; ++s) {
                int n = s * 256 + t;
                if (k > 0 && mkv[s] != -INFINITY) {
                    vfloat4 bx = sh.nms.boxS[n];
                    float xi1 = fmaxf(sx1, bx.x);
                    float yi1 = fmaxf(sy1, bx.y);
                    float xi2 = fminf(sx2, bx.z);
                    float yi2 = fminf(sy2, bx.w);
                    float inter = fmaxf(xi2 - xi1, 0.f) * fmaxf(yi2 - yi1, 0.f);
                    float ar    = (bx.z - bx.x) * (bx.w - bx.y);
                    float uni   = sar + ar - inter;
                    float iou   = inter / fmaxf(uni, 1e-8f);
                    if (iou > 0.3f) mkv[s] = -INFINITY;
                }
                if (mkv[s] != -INFINITY) {
                    unsigned long long kk =
                        ((unsigned long long)__float_as_uint(mkv[s]) << 32) | (unsigned int)(~n);
                    if (kk > best) best = kk;
                }
            }
            #pragma unroll
            for (int off = 32; off > 0; off >>= 1) {
                unsigned long long o2 = __shfl_down(best, off);
                if (o2 > best) best = o2;
            }
            if ((t & 63) == 0) sh.nms.keyB[k & 1][t >> 6] = best;
            __syncthreads();
            unsigned long long m = sh.nms.keyB[k & 1][0];
            #pragma unroll
            for (int w = 1; w < 4; ++w) {
                unsigned long long o2 = sh.nms.keyB[k & 1][w];
                if (o2 > m) m = o2;
            }
            int sel = (m == 0ULL) ? 0 : (int)(~(unsigned int)(m & 0xFFFFFFFFULL));
            if (t == 0) { sh.nms.idxA[k] = sel; sh.nms.okA[k] = (m != 0ULL); }
            vfloat4 sb = sh.nms.boxS[sel];
            sx1 = sb.x; sy1 = sb.y; sx2 = sb.z; sy2 = sb.w;
            sar = (sx2 - sx1) * (sy2 - sy1);
        }
        __syncthreads();          // idxA/okA visible to t0
        if (t == 0) {
            #pragma unroll 1
            for (int k = 0; k < KMAX; ++k) {
                float mm = 0.f;
                for (int k2 = 0; k2 < KMAX; ++k2)
                    if (sh.nms.idxA[k2] == sh.nms.idxA[k] && sh.nms.okA[k2]) mm = 1.f;
                pfT[blk * 32 + k] = sh.nms.prS[sh.nms.idxA[k]] * mm;
            }
            __threadfence();                      // pfT visible device-wide...
            atomicExch(flag, 1);                  // ...before flag flips
        }
        __syncthreads();          // done with sh.nms before spL reuse
    }

    // ============ big units: every block does unit blk; blocks 8-391 take a 2nd ============
    {
        const int u = blk;
        const size_t jb = (size_t)u * 1024 + (size_t)t * 4;
        const int b = u / 144;
        vfloat4 m = stage_unit(wlg, jb, sh.spL, t);   // ~30us of reads hides the flag wait
        if (t == 0) {
            while (atomicAdd(flag, 0) == 0) { __builtin_amdgcn_s_sleep(8); }
            __threadfence();
        }
        __syncthreads();
        write_unit(out, pfT + b * 32, jb, sh.spL, t, m);
    }
    if (blk >= 8 && blk < 8 + (UNITS - GRID)) {       // blocks 8..391 -> units 768..1151
        const int u = GRID + (blk - 8);
        const size_t jb = (size_t)u * 1024 + (size_t)t * 4;
        const int b = u / 144;
        vfloat4 m = stage_unit(wlg, jb, sh.spL, t);   // thread-private slots: no barrier needed
        write_unit(out, pfT + b * 32, jb, sh.spL, t, m);
    }
}

extern "C" void kernel_launch(void* const* d_in, const int* in_sizes, int n_in,
                              void* d_out, int out_size, void* d_ws, size_t ws_size,
                              hipStream_t stream)
{
    const float* zwhere = (const float*)d_in[0];
    const float* w_zw   = (const float*)d_in[1];
    const float* b_zw   = (const float*)d_in[2];
    const float* logit  = (const float*)d_in[3];
    const float* w_lg   = (const float*)d_in[4];
    const float* b_lg   = (const float*)d_in[5];
    const float* wlogit = (const float*)d_in[6];
    float* out = (float*)d_out;
    float* pfT = (float*)d_ws;                    // [8][32] prob_few
    int*   flag = (int*)((char*)d_ws + 1024);     // 4-byte sync flag

    hipMemsetAsync(flag, 0, 4, stream);           // capturable memset node, per-replay reset
    fused_kernel<<<GRID, 256, 0, stream>>>(zwhere, w_zw, b_zw, logit, w_lg, b_lg,
                                           wlogit, pfT, flag, out);
}